// Round 8
// baseline (65.183 us; speedup 1.0000x reference)
//
#include <hip/hip_runtime.h>
#include <hip/hip_cooperative_groups.h>

namespace cg = cooperative_groups;

// SDF Chamfer loss, H=W=64, 2 images. ONE cooperative kernel.
// Blocks 0..251: self-extract + chamfer partial (imgset = blk/63, qblk = blk%63).
// Blocks 252..253: L1 sum for image (blk-252). Blocks 254..255: idle.
// grid.sync(); block 0 reduces and writes out[0].
// ws float layout:
//   [0..3]    int: masked count per imgset (published by qblk==0 blocks)
//   [8..9]    L1 sums per image
//   [64..315] chamfer partial sums, one per chamfer block (252)
#define HH 64
#define WW 64
#define NV ((HH-1)*WW)        // 4032
#define NP (NV + HH*(WW-1))   // 8064
#define NQB 63                // query blocks per imgset
#define QPB 128               // query edges per block (63*128 = 8064)
#define EPSF 1e-8f
#define BIGF 3.0e38f
#define L1_OFF 8
#define PART_OFF 64

__device__ __forceinline__ void edge_point(const float* __restrict__ sdf, int e,
                                           float& R, float& C, bool& m) {
    float v1, v2;
    if (e < NV) {                       // vertical: rows i, i+1
        int i = e >> 6, j = e & 63;
        v1 = sdf[i * WW + j];
        v2 = sdf[i * WW + WW + j];
        float a = fabsf(v1) / (fabsf(v1) + fabsf(v2) + EPSF);
        float frac = (v1 == 0.f) ? 0.f : ((v2 == 0.f) ? 1.f : a);
        R = (float)i + frac; C = (float)j;
    } else {                            // horizontal: cols j, j+1
        int eh = e - NV;
        int i = eh / (WW - 1), j = eh % (WW - 1);
        v1 = sdf[i * WW + j];
        v2 = sdf[i * WW + j + 1];
        float a = fabsf(v1) / (fabsf(v1) + fabsf(v2) + EPSF);
        float frac = (v1 == 0.f) ? 0.f : ((v2 == 0.f) ? 1.f : a);
        R = (float)i; C = (float)j + frac;
    }
    m = (v1 == 0.f) || (v2 == 0.f) || (v1 * v2 < 0.f);
}

__global__ __launch_bounds__(512) void fused_all(const float* __restrict__ pred,
                                                 const float* __restrict__ gt,
                                                 float* __restrict__ ws,
                                                 float* __restrict__ out) {
    int blk = blockIdx.x;
    int tid = threadIdx.x, lane = tid & 63, wid = tid >> 6;
    cg::grid_group grid = cg::this_grid();

    __shared__ __align__(16) float2 ctile[NP + 16];
    __shared__ __align__(16) float2 qpts[QPB];
    __shared__ int wcnt[8];
    __shared__ int qc_s[2];
    __shared__ float red[8];

    if (blk < 4 * NQB) {
        // ---------------- chamfer block ----------------
        int imgset = blk / NQB;
        int qblk = blk - imgset * NQB;
        int opp = imgset ^ 1;
        const float* csdf = ((opp & 1) ? gt : pred) + (opp >> 1) * (HH * WW);
        const float* qsdf = ((imgset & 1) ? gt : pred) + (imgset >> 1) * (HH * WW);
        unsigned long long lt = (1ull << lane) - 1ull;

        // query extraction + 2-wave ballot compaction (tid < 128)
        float QR = 0.f, QC = 0.f; bool qm = false;
        if (tid < QPB) edge_point(qsdf, qblk * QPB + tid, QR, QC, qm);
        unsigned long long qb = __ballot(qm);
        if (tid < QPB && lane == 0) qc_s[wid] = __popcll(qb);
        __syncthreads();
        int qcnt = qc_s[0] + qc_s[1];
        if (qm) qpts[(wid == 1 ? qc_s[0] : 0) + __popcll(qb & lt)] = make_float2(QR, QC);

        // candidate extraction: 16 chunks of 512, block-wide compaction
        int ccnt = 0;
        for (int chunk = 0; chunk < 16; ++chunk) {
            int e = (chunk << 9) + tid;
            float R = 0.f, C = 0.f; bool m = false;
            if (e < NP) edge_point(csdf, e, R, C, m);
            unsigned long long b = __ballot(m);
            if (lane == 0) wcnt[wid] = __popcll(b);
            __syncthreads();
            int off = ccnt, tot = 0;
            #pragma unroll
            for (int w = 0; w < 8; ++w) { int c = wcnt[w]; if (w < wid) off += c; tot += c; }
            if (m) ctile[off + __popcll(b & lt)] = make_float2(R, C);
            ccnt += tot;
            __syncthreads();
        }
        int P2 = (ccnt + 31) & ~31;
        for (int i = ccnt + tid; i < P2; i += 512) ctile[i] = make_float2(1e9f, 1e9f);
        if (tid == 0 && qblk == 0)
            __hip_atomic_store((int*)ws + opp, ccnt, __ATOMIC_RELAXED,
                               __HIP_MEMORY_SCOPE_AGENT);
        __syncthreads();

        // chamfer: 64 slots x 8 threads, 4 indep min chains, 2 passes
        int slot = tid >> 3, r = tid & 7;
        const float4* t4 = (const float4*)ctile;
        int kmax = P2 >> 5;
        float acc = 0.f;
        for (int pass = 0; pass < 2; ++pass) {
            if (pass == 1 && qcnt <= 64) break;        // block-uniform
            int q = pass * 64 + slot;
            bool v = q < qcnt;
            float2 qp = v ? qpts[q] : make_float2(1e8f, 1e8f);
            float m0 = BIGF, m1 = BIGF, m2 = BIGF, m3 = BIGF;
            for (int k = 0; k < kmax; ++k) {           // 4 candidates/thread/iter
                float4 a = t4[k * 16 + r];
                float4 c = t4[k * 16 + 8 + r];
                float dx0 = qp.x - a.x, dy0 = qp.y - a.y;
                float dx1 = qp.x - a.z, dy1 = qp.y - a.w;
                float dx2 = qp.x - c.x, dy2 = qp.y - c.y;
                float dx3 = qp.x - c.z, dy3 = qp.y - c.w;
                m0 = fminf(m0, __builtin_fmaf(dx0, dx0, dy0 * dy0));
                m1 = fminf(m1, __builtin_fmaf(dx1, dx1, dy1 * dy1));
                m2 = fminf(m2, __builtin_fmaf(dx2, dx2, dy2 * dy2));
                m3 = fminf(m3, __builtin_fmaf(dx3, dx3, dy3 * dy3));
            }
            float m = fminf(fminf(m0, m1), fminf(m2, m3));
            m = fminf(m, __shfl_xor(m, 1, 64));        // combine 8 r-lanes
            m = fminf(m, __shfl_xor(m, 2, 64));
            m = fminf(m, __shfl_xor(m, 4, 64));
            if (v && r == 0) acc += sqrtf(m);
        }

        for (int o = 32; o; o >>= 1) acc += __shfl_down(acc, o, 64);
        if (lane == 0) red[wid] = acc;
        __syncthreads();
        if (tid == 0) {
            float s = 0.f;
            #pragma unroll
            for (int w = 0; w < 8; ++w) s += red[w];
            __hip_atomic_store(&ws[PART_OFF + blk], s, __ATOMIC_RELAXED,
                               __HIP_MEMORY_SCOPE_AGENT);
        }
    } else if (blk < 4 * NQB + 2) {
        // ---------------- L1 block (one per image) ----------------
        int img = blk - 4 * NQB;
        const float4* p4 = (const float4*)(pred + img * (HH * WW));
        const float4* g4 = (const float4*)(gt + img * (HH * WW));
        float s = 0.f;
        #pragma unroll
        for (int j = 0; j < 2; ++j) {                  // 1024 float4 per image
            int idx = tid + j * 512;
            float4 a = p4[idx], b = g4[idx];
            s += fabsf(a.x - b.x) + fabsf(a.y - b.y) + fabsf(a.z - b.z) + fabsf(a.w - b.w);
        }
        for (int o = 32; o; o >>= 1) s += __shfl_down(s, o, 64);
        if (lane == 0) red[wid] = s;
        __syncthreads();
        if (tid == 0) {
            float t = 0.f;
            #pragma unroll
            for (int w = 0; w < 8; ++w) t += red[w];
            __hip_atomic_store(&ws[L1_OFF + img], t, __ATOMIC_RELAXED,
                               __HIP_MEMORY_SCOPE_AGENT);
        }
    }

    grid.sync();

    // ---------------- finalize: block 0 only ----------------
    if (blk != 0) return;
    float v = 0.f;
    if (wid < 4 && lane < NQB)
        v = __hip_atomic_load(&ws[PART_OFF + wid * NQB + lane], __ATOMIC_RELAXED,
                              __HIP_MEMORY_SCOPE_AGENT);
    for (int o = 32; o; o >>= 1) v += __shfl_down(v, o, 64);
    __syncthreads();                                   // red reuse guard
    if (lane == 0) red[wid] = v;
    __syncthreads();
    if (tid == 0) {
        float loss = 0.f;
        for (int b = 0; b < 2; ++b) {
            int c0 = __hip_atomic_load((int*)ws + 2 * b + 0, __ATOMIC_RELAXED,
                                       __HIP_MEMORY_SCOPE_AGENT);
            int c1 = __hip_atomic_load((int*)ws + 2 * b + 1, __ATOMIC_RELAXED,
                                       __HIP_MEMORY_SCOPE_AGENT);
            float l1 = __hip_atomic_load(&ws[L1_OFF + b], __ATOMIC_RELAXED,
                                         __HIP_MEMORY_SCOPE_AGENT);
            float mean1 = red[2 * b + 0] / fmaxf((float)c0, 1.f);   // pred->gt
            float mean2 = red[2 * b + 1] / fmaxf((float)c1, 1.f);   // gt->pred
            loss += l1 * (1.f / (HH * WW)) + fabsf(-mean1 + mean2);
        }
        out[0] = loss * 0.5f;
    }
}

extern "C" void kernel_launch(void* const* d_in, const int* in_sizes, int n_in,
                              void* d_out, int out_size, void* d_ws, size_t ws_size,
                              hipStream_t stream) {
    const float* pred = (const float*)d_in[0];
    const float* gt   = (const float*)d_in[1];
    float* ws  = (float*)d_ws;
    float* out = (float*)d_out;

    void* args[] = {(void*)&pred, (void*)&gt, (void*)&ws, (void*)&out};
    hipLaunchCooperativeKernel((const void*)fused_all,
                               dim3(4 * NQB + 4), dim3(512), args, 0, stream);
}

// Round 9
// 23.665 us; speedup vs baseline: 2.7545x; 2.7545x over previous
//
#include <hip/hip_runtime.h>

// SDF Chamfer loss, H=W=64, 2 images. Grid-binned exact nearest neighbor.
// Each 1x1 cell holds <=4 zero-crossing points (proof: a cell (a,b) can only
// receive the vertical edge of (a,b) [frac<1], vertical of (a-1,b) [frac==1],
// horizontal of (a,b) [frac<1], horizontal of (a,b-1) [frac==1]).
// Query = exact expanding-ring search: after scanning Chebyshev ring r, any
// unscanned point has distance > r, so stop when best^2 <= r^2.
// ws float layout:
//   [0..3]    int: masked count per imgset
//   [16..143] query-block partial sums (128)
//   [256..]   cell tables: imgset*32768 floats; 4096 cells x 4 slots x float2,
//             unused slots = (1e9,1e9) sentinel (rewritten every call)
#define HH 64
#define WW 64
#define NV ((HH-1)*WW)        // 4032
#define NP (NV + HH*(WW-1))   // 8064
#define EPSF 1e-8f
#define BIGF 3.0e38f
#define SENTC 1e9f
#define CNT_OFF 0
#define PART_OFF 16
#define CELL_OFF 256
#define CELLS_PER_SET (4096 * 4)   // float2 slots

__device__ __forceinline__ void edge_point(const float* __restrict__ sdf, int e,
                                           float& R, float& C, bool& m) {
    float v1, v2;
    if (e < NV) {                       // vertical: rows i, i+1
        int i = e >> 6, j = e & 63;
        v1 = sdf[i * WW + j];
        v2 = sdf[i * WW + WW + j];
        float a = fabsf(v1) / (fabsf(v1) + fabsf(v2) + EPSF);
        float frac = (v1 == 0.f) ? 0.f : ((v2 == 0.f) ? 1.f : a);
        R = (float)i + frac; C = (float)j;
    } else {                            // horizontal: cols j, j+1
        int eh = e - NV;
        int i = eh / (WW - 1), j = eh % (WW - 1);
        v1 = sdf[i * WW + j];
        v2 = sdf[i * WW + j + 1];
        float a = fabsf(v1) / (fabsf(v1) + fabsf(v2) + EPSF);
        float frac = (v1 == 0.f) ? 0.f : ((v2 == 0.f) ? 1.f : a);
        R = (float)i; C = (float)j + frac;
    }
    m = (v1 == 0.f) || (v2 == 0.f) || (v1 * v2 < 0.f);
}

// grid: 4 blocks (one per imgset), 1024 threads. Builds the cell table.
__global__ __launch_bounds__(1024) void build_kernel(const float* __restrict__ pred,
                                                     const float* __restrict__ gt,
                                                     float* __restrict__ ws) {
    int imgset = blockIdx.x;
    int b = imgset >> 1, set = imgset & 1;
    const float* sdf = (set ? gt : pred) + b * (HH * WW);
    int tid = threadIdx.x, lane = tid & 63, wid = tid >> 6;
    __shared__ int cnt[4096];
    #pragma unroll
    for (int k = 0; k < 4; ++k) cnt[tid + k * 1024] = 0;
    __syncthreads();

    float2* cells = (float2*)(ws + CELL_OFF) + imgset * CELLS_PER_SET;
    int my = 0;
    for (int e = tid; e < NP; e += 1024) {
        float R, C; bool m;
        edge_point(sdf, e, R, C, m);
        if (m) {
            ++my;
            int cell = ((int)R << 6) + (int)C;      // floor; R,C in [0,63]
            int slot = atomicAdd(&cnt[cell], 1);    // LDS atomic; order-free (min)
            if (slot < 4) cells[cell * 4 + slot] = make_float2(R, C);
        }
    }
    __syncthreads();
    // sentinel-fill unused slots (no overlap with point writes)
    #pragma unroll
    for (int k = 0; k < 4; ++k) {
        int cell = tid + k * 1024;
        int c = cnt[cell];
        for (int s = c; s < 4; ++s) cells[cell * 4 + s] = make_float2(SENTC, SENTC);
    }
    // total masked count
    for (int o = 32; o; o >>= 1) my += __shfl_down(my, o, 64);
    __shared__ int red[16];
    if (lane == 0) red[wid] = my;
    __syncthreads();
    if (tid == 0) {
        int t = 0;
        #pragma unroll
        for (int w = 0; w < 16; ++w) t += red[w];
        ((int*)ws)[CNT_OFF + imgset] = t;
    }
}

__device__ __forceinline__ void scan_cell(const float2* __restrict__ cells, int cell,
                                          float qx, float qy, float& best) {
    const float4* cp = (const float4*)(cells + cell * 4);
    float4 a = cp[0], c = cp[1];
    float dx0 = qx - a.x, dy0 = qy - a.y, dx1 = qx - a.z, dy1 = qy - a.w;
    float dx2 = qx - c.x, dy2 = qy - c.y, dx3 = qx - c.z, dy3 = qy - c.w;
    float d0 = __builtin_fmaf(dx0, dx0, dy0 * dy0);
    float d1 = __builtin_fmaf(dx1, dx1, dy1 * dy1);
    float d2 = __builtin_fmaf(dx2, dx2, dy2 * dy2);
    float d3 = __builtin_fmaf(dx3, dx3, dy3 * dy3);
    best = fminf(best, fminf(fminf(d0, d1), fminf(d2, d3)));
}

// grid: 128 blocks = imgset(4) x 32, 256 threads; 1 query edge per thread.
__global__ __launch_bounds__(256) void query_kernel(const float* __restrict__ pred,
                                                    const float* __restrict__ gt,
                                                    float* __restrict__ ws) {
    int blk = blockIdx.x;
    int imgset = blk >> 5;
    int e = ((blk & 31) << 8) + threadIdx.x;
    int b = imgset >> 1, set = imgset & 1;
    const float* sdf = (set ? gt : pred) + b * (HH * WW);
    const float2* cells = (const float2*)(ws + CELL_OFF) + (imgset ^ 1) * CELLS_PER_SET;

    float acc = 0.f;
    if (e < NP) {
        float R, C; bool m;
        edge_point(sdf, e, R, C, m);
        if (m) {
            float best = BIGF;
            int ci = (int)R, cj = (int)C;
            // rings 0-1: 9 cells, branch-free evals, loads batched in flight
            #pragma unroll
            for (int di = -1; di <= 1; ++di) {
                #pragma unroll
                for (int dj = -1; dj <= 1; ++dj) {
                    int i = ci + di, j = cj + dj;
                    if ((unsigned)i < 64u && (unsigned)j < 64u)
                        scan_cell(cells, (i << 6) + j, R, C, best);
                }
            }
            // rings >= 2 (rare: ~4% of lanes hit r=2, ~0 hit r=3)
            for (int r = 2; r < 64 && best > (float)((r - 1) * (r - 1)); ++r) {
                int ilo = max(ci - r, 0), ihi = min(ci + r, 63);
                int jlo = max(cj - r, 0), jhi = min(cj + r, 63);
                for (int i = ilo; i <= ihi; ++i) {
                    if (i == ci - r || i == ci + r) {
                        for (int j = jlo; j <= jhi; ++j)
                            scan_cell(cells, (i << 6) + j, R, C, best);
                    } else {
                        if (cj - r >= 0) scan_cell(cells, (i << 6) + (cj - r), R, C, best);
                        if (cj + r <= 63) scan_cell(cells, (i << 6) + (cj + r), R, C, best);
                    }
                }
            }
            acc = sqrtf(best);
        }
    }
    int lane = threadIdx.x & 63, wid = threadIdx.x >> 6;
    for (int o = 32; o; o >>= 1) acc += __shfl_down(acc, o, 64);
    __shared__ float red[4];
    if (lane == 0) red[wid] = acc;
    __syncthreads();
    if (threadIdx.x == 0) ws[PART_OFF + blk] = red[0] + red[1] + red[2] + red[3];
}

// 1 block, 256 threads: combine 128 partials + counts + L1 + final loss.
__global__ __launch_bounds__(256) void tail_kernel(const float* __restrict__ ws,
                                                   const float* __restrict__ pred,
                                                   const float* __restrict__ gt,
                                                   float* __restrict__ out) {
    int tid = threadIdx.x, lane = tid & 63, wid = tid >> 6;
    const int* cnts = (const int*)ws;
    __shared__ float sums[4];
    __shared__ float red[8];

    // chamfer sums: wave w owns imgset w's 32 partials
    float v = (lane < 32) ? ws[PART_OFF + wid * 32 + lane] : 0.f;
    for (int o = 32; o; o >>= 1) v += __shfl_down(v, o, 64);
    if (lane == 0) sums[wid] = v;

    // L1 from inputs: 2048 float4 spans both images (1024 per image)
    const float4* p4 = (const float4*)pred;
    const float4* g4 = (const float4*)gt;
    float s0 = 0.f, s1 = 0.f;
    #pragma unroll
    for (int j = 0; j < 8; ++j) {
        int idx = tid + j * 256;
        float4 a = p4[idx], bb = g4[idx];
        float t = fabsf(a.x - bb.x) + fabsf(a.y - bb.y) + fabsf(a.z - bb.z) + fabsf(a.w - bb.w);
        if (j < 4) s0 += t; else s1 += t;
    }
    for (int o = 32; o; o >>= 1) { s0 += __shfl_down(s0, o, 64); s1 += __shfl_down(s1, o, 64); }
    __syncthreads();
    if (lane == 0) { red[wid] = s0; red[4 + wid] = s1; }
    __syncthreads();

    if (tid == 0) {
        float l1a = red[0] + red[1] + red[2] + red[3];
        float l1b = red[4] + red[5] + red[6] + red[7];
        float loss = 0.f;
        for (int b = 0; b < 2; ++b) {
            float mean1 = sums[2 * b + 0] / fmaxf((float)cnts[2 * b + 0], 1.f); // pred->gt
            float mean2 = sums[2 * b + 1] / fmaxf((float)cnts[2 * b + 1], 1.f); // gt->pred
            loss += (b == 0 ? l1a : l1b) * (1.f / (HH * WW)) + fabsf(-mean1 + mean2);
        }
        out[0] = loss * 0.5f;
    }
}

extern "C" void kernel_launch(void* const* d_in, const int* in_sizes, int n_in,
                              void* d_out, int out_size, void* d_ws, size_t ws_size,
                              hipStream_t stream) {
    const float* pred = (const float*)d_in[0];
    const float* gt   = (const float*)d_in[1];
    float* ws  = (float*)d_ws;
    float* out = (float*)d_out;

    hipLaunchKernelGGL(build_kernel, dim3(4),   dim3(1024), 0, stream, pred, gt, ws);
    hipLaunchKernelGGL(query_kernel, dim3(128), dim3(256),  0, stream, pred, gt, ws);
    hipLaunchKernelGGL(tail_kernel,  dim3(1),   dim3(256),  0, stream, ws, pred, gt, out);
}

// Round 10
// 16.139 us; speedup vs baseline: 4.0389x; 1.4663x over previous
//
#include <hip/hip_runtime.h>

// SDF Chamfer loss, H=W=64, 2 images. TWO kernels.
// work_kernel: 32 blocks = imgset(4) x octant(8), 1024 threads. Each block
// builds the OPPOSITE set's cell table in its own LDS (race-free: each of a
// cell's 4 slots has a unique producing edge, so no atomics), then answers its
// 1008 queries via exact expanding-ring search in LDS, plus a 256-px L1 slice.
// Cell-slot proof: cell (a,b) receives only vertical(a,b)[frac<1] -> slot0,
// vertical(a-1,b)[frac==1] -> slot1, horizontal(a,b)[frac<1] -> slot2,
// horizontal(a,b-1)[frac==1] -> slot3.
// Ring-search exactness: after scanning Chebyshev rings <= r, any unscanned
// point is at distance >= r, so stop when best^2 <= r^2.
// ws float layout: [0..31] chamfer partial sums (per block)
//                  [32..63] query-mask counts (per block, float)
//                  [64..95] L1 partial sums (per block; img = blk>>4)
#define HH 64
#define WW 64
#define NV ((HH-1)*WW)        // 4032
#define NP (NV + HH*(WW-1))   // 8064
#define QPB 1008              // queries per block (8 octants x 1008 = 8064)
#define EPSF 1e-8f
#define BIGF 3.0e38f
#define SENTC 1e9f

// Evaluates edge e: point (R,C), mask m, and the unique cell-slot index for
// the build phase (cslot = (cell*4 + slot)).
__device__ __forceinline__ void edge_eval(const float* __restrict__ sdf, int e,
                                          float& R, float& C, bool& m, int& cslot) {
    float v1, v2;
    if (e < NV) {                       // vertical: rows i, i+1
        int i = e >> 6, j = e & 63;
        v1 = sdf[i * WW + j];
        v2 = sdf[i * WW + WW + j];
        float a = fabsf(v1) / (fabsf(v1) + fabsf(v2) + EPSF);
        float frac = (v1 == 0.f) ? 0.f : ((v2 == 0.f) ? 1.f : a);
        R = (float)i + frac; C = (float)j;
        cslot = (frac == 1.f) ? (((((i + 1) << 6) + j) << 2) + 1)
                              : ((((i << 6) + j) << 2) + 0);
    } else {                            // horizontal: cols j, j+1
        int eh = e - NV;
        int i = eh / (WW - 1), j = eh % (WW - 1);
        v1 = sdf[i * WW + j];
        v2 = sdf[i * WW + j + 1];
        float a = fabsf(v1) / (fabsf(v1) + fabsf(v2) + EPSF);
        float frac = (v1 == 0.f) ? 0.f : ((v2 == 0.f) ? 1.f : a);
        R = (float)i; C = (float)j + frac;
        cslot = (frac == 1.f) ? ((((i << 6) + (j + 1)) << 2) + 3)
                              : ((((i << 6) + j) << 2) + 2);
    }
    m = (v1 == 0.f) || (v2 == 0.f) || (v1 * v2 < 0.f);
}

__device__ __forceinline__ void scan_cell_lds(const float2* __restrict__ cells, int cell,
                                              float qx, float qy, float& best) {
    const float4* cp = (const float4*)(cells + (cell << 2));
    float4 a = cp[0], c = cp[1];
    float dx0 = qx - a.x, dy0 = qy - a.y, dx1 = qx - a.z, dy1 = qy - a.w;
    float dx2 = qx - c.x, dy2 = qy - c.y, dx3 = qx - c.z, dy3 = qy - c.w;
    float d0 = __builtin_fmaf(dx0, dx0, dy0 * dy0);
    float d1 = __builtin_fmaf(dx1, dx1, dy1 * dy1);
    float d2 = __builtin_fmaf(dx2, dx2, dy2 * dy2);
    float d3 = __builtin_fmaf(dx3, dx3, dy3 * dy3);
    best = fminf(best, fminf(fminf(d0, d1), fminf(d2, d3)));
}

__global__ __launch_bounds__(1024) void work_kernel(const float* __restrict__ pred,
                                                    const float* __restrict__ gt,
                                                    float* __restrict__ ws) {
    int blk = blockIdx.x;               // 32 blocks
    int imgset = blk >> 3, oct = blk & 7;
    int b = imgset >> 1, set = imgset & 1;
    int opp = imgset ^ 1;
    const float* qsdf = (set ? gt : pred) + b * (HH * WW);
    const float* csdf = ((opp & 1) ? gt : pred) + (opp >> 1) * (HH * WW);
    int tid = threadIdx.x, lane = tid & 63, wid = tid >> 6;

    __shared__ __align__(16) float2 cells[4096 * 4];   // 128 KiB cell table
    __shared__ float redA[16], redB[16], redC[16];

    // sentinel init: 8192 float4, 8 per thread
    float4* c4 = (float4*)cells;
    #pragma unroll
    for (int k = 0; k < 8; ++k)
        c4[tid + k * 1024] = make_float4(SENTC, SENTC, SENTC, SENTC);
    __syncthreads();

    // build opposite table: race-free unique-slot writes, no atomics
    #pragma unroll
    for (int k = 0; k < 8; ++k) {
        int e = tid + k * 1024;
        if (e < NP) {
            float R, C; bool m; int cslot;
            edge_eval(csdf, e, R, C, m, cslot);
            if (m) cells[cslot] = make_float2(R, C);
        }
    }
    __syncthreads();

    // query own octant: 1 query per thread (threads 1008..1023 idle)
    float acc = 0.f, mycnt = 0.f;
    if (tid < QPB) {
        int e = oct * QPB + tid;
        float R, C; bool m; int cs;
        edge_eval(qsdf, e, R, C, m, cs);
        if (m) {
            mycnt = 1.f;
            float best = BIGF;
            int ci = (int)R, cj = (int)C;
            // rings 0-1: 9 cells, branch-free evals
            #pragma unroll
            for (int di = -1; di <= 1; ++di) {
                #pragma unroll
                for (int dj = -1; dj <= 1; ++dj) {
                    int i = ci + di, j = cj + dj;
                    if ((unsigned)i < 64u && (unsigned)j < 64u)
                        scan_cell_lds(cells, (i << 6) + j, R, C, best);
                }
            }
            // rings >= 2 (rare)
            for (int r = 2; r < 64 && best > (float)((r - 1) * (r - 1)); ++r) {
                int ilo = max(ci - r, 0), ihi = min(ci + r, 63);
                int jlo = max(cj - r, 0), jhi = min(cj + r, 63);
                for (int i = ilo; i <= ihi; ++i) {
                    if (i == ci - r || i == ci + r) {
                        for (int j = jlo; j <= jhi; ++j)
                            scan_cell_lds(cells, (i << 6) + j, R, C, best);
                    } else {
                        if (cj - r >= 0) scan_cell_lds(cells, (i << 6) + (cj - r), R, C, best);
                        if (cj + r <= 63) scan_cell_lds(cells, (i << 6) + (cj + r), R, C, best);
                    }
                }
            }
            acc = sqrtf(best);
        }
    }

    // L1 slice: pixels [blk*256, blk*256+256) over flat [8192] (2 images)
    float l1 = 0.f;
    if (tid < 64) {
        const float4* p4 = (const float4*)pred;
        const float4* g4 = (const float4*)gt;
        int idx = blk * 64 + tid;
        float4 a = p4[idx], bb = g4[idx];
        l1 = fabsf(a.x - bb.x) + fabsf(a.y - bb.y) + fabsf(a.z - bb.z) + fabsf(a.w - bb.w);
    }

    // block reduce (1024 threads, 16 waves)
    for (int o = 32; o; o >>= 1) {
        acc   += __shfl_down(acc, o, 64);
        mycnt += __shfl_down(mycnt, o, 64);
        l1    += __shfl_down(l1, o, 64);
    }
    if (lane == 0) { redA[wid] = acc; redB[wid] = mycnt; redC[wid] = l1; }
    __syncthreads();
    if (tid == 0) {
        float sA = 0.f, sB = 0.f, sC = 0.f;
        #pragma unroll
        for (int w = 0; w < 16; ++w) { sA += redA[w]; sB += redB[w]; sC += redC[w]; }
        ws[blk] = sA;
        ws[32 + blk] = sB;
        ws[64 + blk] = sC;
    }
}

// 1 block, 256 threads: combine 32 sums/counts/L1 partials -> loss.
__global__ __launch_bounds__(256) void final_kernel(const float* __restrict__ ws,
                                                    float* __restrict__ out) {
    int tid = threadIdx.x, lane = tid & 63, wid = tid >> 6;
    __shared__ float sums[4], cnts[4], l1s[2];

    // wave w owns imgset w: 8 octant partials each
    float v = (lane < 8) ? ws[wid * 8 + lane] : 0.f;
    float c = (lane < 8) ? ws[32 + wid * 8 + lane] : 0.f;
    for (int o = 4; o; o >>= 1) { v += __shfl_down(v, o, 8); c += __shfl_down(c, o, 8); }
    if (lane == 0) { sums[wid] = v; cnts[wid] = c; }

    // L1: waves 0,1 own images 0,1: 16 partials each (img = blk>>4)
    float l = (wid < 2 && lane < 16) ? ws[64 + wid * 16 + lane] : 0.f;
    for (int o = 8; o; o >>= 1) l += __shfl_down(l, o, 16);
    if (wid < 2 && lane == 0) l1s[wid] = l;
    __syncthreads();

    if (tid == 0) {
        float loss = 0.f;
        for (int b = 0; b < 2; ++b) {
            float mean1 = sums[2 * b + 0] / fmaxf(cnts[2 * b + 0], 1.f);  // pred->gt
            float mean2 = sums[2 * b + 1] / fmaxf(cnts[2 * b + 1], 1.f);  // gt->pred
            loss += l1s[b] * (1.f / (HH * WW)) + fabsf(-mean1 + mean2);
        }
        out[0] = loss * 0.5f;
    }
}

extern "C" void kernel_launch(void* const* d_in, const int* in_sizes, int n_in,
                              void* d_out, int out_size, void* d_ws, size_t ws_size,
                              hipStream_t stream) {
    const float* pred = (const float*)d_in[0];
    const float* gt   = (const float*)d_in[1];
    float* ws  = (float*)d_ws;
    float* out = (float*)d_out;

    hipLaunchKernelGGL(work_kernel,  dim3(32), dim3(1024), 0, stream, pred, gt, ws);
    hipLaunchKernelGGL(final_kernel, dim3(1),  dim3(256),  0, stream, ws, out);
}

// Round 11
// 14.190 us; speedup vs baseline: 4.5938x; 1.1374x over previous
//
#include <hip/hip_runtime.h>

// SDF Chamfer loss, H=W=64, 2 images. TWO kernels, 2-slot LDS cell tables.
//
// Cell table: 4096 cells x 2 slots x float2 = 64 KiB per block.
//   slot0 <- vertical edges, slot1 <- horizontal edges, at cell floor(point).
//   Why 2 slots suffice (exact, all inputs): a frac==1 point requires v2==0,
//   and then the adjacent edge (v1==0, frac==0) produces the IDENTICAL point
//   into the same slot -> all write races carry identical values (checked for
//   interior + boundary rows/cols) -> deterministic, no points lost.
// Query: exact expanding Chebyshev-ring search; after scanning rings <= r,
//   any unscanned point is at distance >= r, so stop when best^2 <= r^2.
//
// work_kernel: 64 blocks = imgset(4) x sub(16), 1024 threads. Each block
//   builds the OPPOSITE set's table in its own LDS, answers 504 queries,
//   plus a 128-px L1 slice. final_kernel combines.
// ws float layout: [0..63] chamfer partial sums   (per block)
//                  [64..127] query-mask counts    (per block)
//                  [128..191] L1 partial sums     (per block; img = blk>>5)
#define HH 64
#define WW 64
#define NV ((HH-1)*WW)        // 4032
#define NP (NV + HH*(WW-1))   // 8064
#define QPB 504               // queries per block (16 subs x 504 = 8064)
#define EPSF 1e-8f
#define BIGF 3.0e38f
#define SENTC 1e9f

// point (R,C), mask m, and 2-slot cell index: cslot = cell*2 + axis.
__device__ __forceinline__ void edge_eval(const float* __restrict__ sdf, int e,
                                          float& R, float& C, bool& m, int& cslot) {
    float v1, v2;
    if (e < NV) {                       // vertical: rows i, i+1
        int i = e >> 6, j = e & 63;
        v1 = sdf[i * WW + j];
        v2 = sdf[i * WW + WW + j];
        float a = fabsf(v1) / (fabsf(v1) + fabsf(v2) + EPSF);
        float frac = (v1 == 0.f) ? 0.f : ((v2 == 0.f) ? 1.f : a);
        R = (float)i + frac; C = (float)j;
        cslot = ((((int)R) << 6) + j) << 1;           // floor(R): i or i+1
    } else {                            // horizontal: cols j, j+1
        int eh = e - NV;
        int i = eh / (WW - 1), j = eh % (WW - 1);
        v1 = sdf[i * WW + j];
        v2 = sdf[i * WW + j + 1];
        float a = fabsf(v1) / (fabsf(v1) + fabsf(v2) + EPSF);
        float frac = (v1 == 0.f) ? 0.f : ((v2 == 0.f) ? 1.f : a);
        R = (float)i; C = (float)j + frac;
        cslot = (((i << 6) + (int)C) << 1) | 1;       // floor(C): j or j+1
    }
    m = (v1 == 0.f) || (v2 == 0.f) || (v1 * v2 < 0.f);
}

__device__ __forceinline__ void scan_cell(const float2* __restrict__ cells, int cell,
                                          float qx, float qy, float& best) {
    float4 a = ((const float4*)cells)[cell];          // both slots in one read
    float dx0 = qx - a.x, dy0 = qy - a.y, dx1 = qx - a.z, dy1 = qy - a.w;
    float d0 = __builtin_fmaf(dx0, dx0, dy0 * dy0);
    float d1 = __builtin_fmaf(dx1, dx1, dy1 * dy1);
    best = fminf(best, fminf(d0, d1));
}

__global__ __launch_bounds__(1024) void work_kernel(const float* __restrict__ pred,
                                                    const float* __restrict__ gt,
                                                    float* __restrict__ ws) {
    int blk = blockIdx.x;               // 64 blocks
    int imgset = blk >> 4, sub = blk & 15;
    int b = imgset >> 1, set = imgset & 1;
    int opp = imgset ^ 1;
    const float* qsdf = (set ? gt : pred) + b * (HH * WW);
    const float* csdf = ((opp & 1) ? gt : pred) + (opp >> 1) * (HH * WW);
    int tid = threadIdx.x, lane = tid & 63, wid = tid >> 6;

    __shared__ __align__(16) float2 cells[4096 * 2];  // 64 KiB table
    __shared__ float redA[16], redB[16], redC[16];

    // sentinel init: 4096 float4, 4 per thread
    float4* c4 = (float4*)cells;
    #pragma unroll
    for (int k = 0; k < 4; ++k)
        c4[tid + k * 1024] = make_float4(SENTC, SENTC, SENTC, SENTC);
    __syncthreads();

    // build opposite table: all write races carry identical values
    #pragma unroll
    for (int k = 0; k < 8; ++k) {
        int e = tid + k * 1024;
        if (e < NP) {
            float R, C; bool m; int cslot;
            edge_eval(csdf, e, R, C, m, cslot);
            if (m) cells[cslot] = make_float2(R, C);
        }
    }
    __syncthreads();

    // query own 504-edge slice: 1 query per thread
    float acc = 0.f, mycnt = 0.f;
    if (tid < QPB) {
        int e = sub * QPB + tid;
        float R, C; bool m; int cs;
        edge_eval(qsdf, e, R, C, m, cs);
        if (m) {
            mycnt = 1.f;
            float best = BIGF;
            int ci = (int)R, cj = (int)C;
            // rings 0-1: 9 cells, 9 independent float4 loads
            #pragma unroll
            for (int di = -1; di <= 1; ++di) {
                #pragma unroll
                for (int dj = -1; dj <= 1; ++dj) {
                    int i = ci + di, j = cj + dj;
                    if ((unsigned)i < 64u && (unsigned)j < 64u)
                        scan_cell(cells, (i << 6) + j, R, C, best);
                }
            }
            // rings >= 2 (rare)
            for (int r = 2; r < 64 && best > (float)((r - 1) * (r - 1)); ++r) {
                int ilo = max(ci - r, 0), ihi = min(ci + r, 63);
                int jlo = max(cj - r, 0), jhi = min(cj + r, 63);
                for (int i = ilo; i <= ihi; ++i) {
                    if (i == ci - r || i == ci + r) {
                        for (int j = jlo; j <= jhi; ++j)
                            scan_cell(cells, (i << 6) + j, R, C, best);
                    } else {
                        if (cj - r >= 0) scan_cell(cells, (i << 6) + (cj - r), R, C, best);
                        if (cj + r <= 63) scan_cell(cells, (i << 6) + (cj + r), R, C, best);
                    }
                }
            }
            acc = sqrtf(best);
        }
    }

    // L1 slice: 32 float4 per block over flat [2048] float4 (2 images)
    float l1 = 0.f;
    if (tid < 32) {
        const float4* p4 = (const float4*)pred;
        const float4* g4 = (const float4*)gt;
        int idx = blk * 32 + tid;
        float4 a = p4[idx], bb = g4[idx];
        l1 = fabsf(a.x - bb.x) + fabsf(a.y - bb.y) + fabsf(a.z - bb.z) + fabsf(a.w - bb.w);
    }

    // block reduce (16 waves)
    for (int o = 32; o; o >>= 1) {
        acc   += __shfl_down(acc, o, 64);
        mycnt += __shfl_down(mycnt, o, 64);
        l1    += __shfl_down(l1, o, 64);
    }
    if (lane == 0) { redA[wid] = acc; redB[wid] = mycnt; redC[wid] = l1; }
    __syncthreads();
    if (tid == 0) {
        float sA = 0.f, sB = 0.f, sC = 0.f;
        #pragma unroll
        for (int w = 0; w < 16; ++w) { sA += redA[w]; sB += redB[w]; sC += redC[w]; }
        ws[blk] = sA;
        ws[64 + blk] = sB;
        ws[128 + blk] = sC;
    }
}

// 1 block, 256 threads: combine 64 sums/counts/L1 partials -> loss.
__global__ __launch_bounds__(256) void final_kernel(const float* __restrict__ ws,
                                                    float* __restrict__ out) {
    int tid = threadIdx.x, lane = tid & 63, wid = tid >> 6;
    __shared__ float sums[4], cnts[4], l1s[2];

    // wave w owns imgset w: 16 partials each
    float v = (lane < 16) ? ws[wid * 16 + lane] : 0.f;
    float c = (lane < 16) ? ws[64 + wid * 16 + lane] : 0.f;
    for (int o = 8; o; o >>= 1) { v += __shfl_down(v, o, 16); c += __shfl_down(c, o, 16); }
    if (lane == 0) { sums[wid] = v; cnts[wid] = c; }

    // L1: waves 0,1 own images 0,1: 32 partials each (img = blk>>5)
    float l = (wid < 2 && lane < 32) ? ws[128 + wid * 32 + lane] : 0.f;
    for (int o = 16; o; o >>= 1) l += __shfl_down(l, o, 32);
    if (wid < 2 && lane == 0) l1s[wid] = l;
    __syncthreads();

    if (tid == 0) {
        float loss = 0.f;
        for (int b = 0; b < 2; ++b) {
            float mean1 = sums[2 * b + 0] / fmaxf(cnts[2 * b + 0], 1.f);  // pred->gt
            float mean2 = sums[2 * b + 1] / fmaxf(cnts[2 * b + 1], 1.f);  // gt->pred
            loss += l1s[b] * (1.f / (HH * WW)) + fabsf(-mean1 + mean2);
        }
        out[0] = loss * 0.5f;
    }
}

extern "C" void kernel_launch(void* const* d_in, const int* in_sizes, int n_in,
                              void* d_out, int out_size, void* d_ws, size_t ws_size,
                              hipStream_t stream) {
    const float* pred = (const float*)d_in[0];
    const float* gt   = (const float*)d_in[1];
    float* ws  = (float*)d_ws;
    float* out = (float*)d_out;

    hipLaunchKernelGGL(work_kernel,  dim3(64), dim3(1024), 0, stream, pred, gt, ws);
    hipLaunchKernelGGL(final_kernel, dim3(1),  dim3(256),  0, stream, ws, out);
}

// Round 12
// 13.973 us; speedup vs baseline: 4.6649x; 1.0155x over previous
//
#include <hip/hip_runtime.h>

// SDF Chamfer loss, H=W=64, 2 images. TWO kernels, 2-slot LDS cell tables.
//
// Cell table: 4096 cells x 2 slots x float2 = 64 KiB per block.
//   slot0 <- vertical edges, slot1 <- horizontal edges, at cell floor(point).
//   2 slots are exact for all inputs: a frac==1 point requires v2==0, and the
//   adjacent edge (v1==0, frac==0) then produces the IDENTICAL point into the
//   same slot -> all write races carry identical values -> deterministic.
// Query: exact expanding Chebyshev-ring search; after scanning rings <= r,
//   any unscanned point is at distance >= r, so stop when best^2 <= r^2.
//
// work_kernel: 128 blocks = imgset(4) x sub(32), 1024 threads. Each block
//   builds the OPPOSITE set's table in its own LDS, answers 252 queries,
//   plus a 64-px L1 slice. final_kernel combines.
// ws float layout: [0..127]   chamfer partial sums (per block)
//                  [128..255] query-mask counts    (per block)
//                  [256..383] L1 partial sums      (per block; img = blk>>6)
#define HH 64
#define WW 64
#define NV ((HH-1)*WW)        // 4032
#define NP (NV + HH*(WW-1))   // 8064
#define QPB 252               // queries per block (32 subs x 252 = 8064)
#define EPSF 1e-8f
#define BIGF 3.0e38f
#define SENTC 1e9f

// point (R,C), mask m, and 2-slot cell index: cslot = cell*2 + axis.
__device__ __forceinline__ void edge_eval(const float* __restrict__ sdf, int e,
                                          float& R, float& C, bool& m, int& cslot) {
    float v1, v2;
    if (e < NV) {                       // vertical: rows i, i+1
        int i = e >> 6, j = e & 63;
        v1 = sdf[i * WW + j];
        v2 = sdf[i * WW + WW + j];
        float a = fabsf(v1) / (fabsf(v1) + fabsf(v2) + EPSF);
        float frac = (v1 == 0.f) ? 0.f : ((v2 == 0.f) ? 1.f : a);
        R = (float)i + frac; C = (float)j;
        cslot = ((((int)R) << 6) + j) << 1;           // floor(R): i or i+1
    } else {                            // horizontal: cols j, j+1
        int eh = e - NV;
        int i = eh / (WW - 1), j = eh % (WW - 1);
        v1 = sdf[i * WW + j];
        v2 = sdf[i * WW + j + 1];
        float a = fabsf(v1) / (fabsf(v1) + fabsf(v2) + EPSF);
        float frac = (v1 == 0.f) ? 0.f : ((v2 == 0.f) ? 1.f : a);
        R = (float)i; C = (float)j + frac;
        cslot = (((i << 6) + (int)C) << 1) | 1;       // floor(C): j or j+1
    }
    m = (v1 == 0.f) || (v2 == 0.f) || (v1 * v2 < 0.f);
}

__device__ __forceinline__ void scan_cell(const float2* __restrict__ cells, int cell,
                                          float qx, float qy, float& best) {
    float4 a = ((const float4*)cells)[cell];          // both slots in one read
    float dx0 = qx - a.x, dy0 = qy - a.y, dx1 = qx - a.z, dy1 = qy - a.w;
    float d0 = __builtin_fmaf(dx0, dx0, dy0 * dy0);
    float d1 = __builtin_fmaf(dx1, dx1, dy1 * dy1);
    best = fminf(best, fminf(d0, d1));
}

__global__ __launch_bounds__(1024) void work_kernel(const float* __restrict__ pred,
                                                    const float* __restrict__ gt,
                                                    float* __restrict__ ws) {
    int blk = blockIdx.x;               // 128 blocks
    int imgset = blk >> 5, sub = blk & 31;
    int b = imgset >> 1, set = imgset & 1;
    int opp = imgset ^ 1;
    const float* qsdf = (set ? gt : pred) + b * (HH * WW);
    const float* csdf = ((opp & 1) ? gt : pred) + (opp >> 1) * (HH * WW);
    int tid = threadIdx.x, lane = tid & 63, wid = tid >> 6;

    __shared__ __align__(16) float2 cells[4096 * 2];  // 64 KiB table
    __shared__ float redA[16], redB[16], redC[16];

    // sentinel init: 4096 float4, 4 per thread
    float4* c4 = (float4*)cells;
    #pragma unroll
    for (int k = 0; k < 4; ++k)
        c4[tid + k * 1024] = make_float4(SENTC, SENTC, SENTC, SENTC);
    __syncthreads();

    // build opposite table: all write races carry identical values
    #pragma unroll
    for (int k = 0; k < 8; ++k) {
        int e = tid + k * 1024;
        if (e < NP) {
            float R, C; bool m; int cslot;
            edge_eval(csdf, e, R, C, m, cslot);
            if (m) cells[cslot] = make_float2(R, C);
        }
    }
    __syncthreads();

    // query own 252-edge slice: 1 query per thread
    float acc = 0.f, mycnt = 0.f;
    if (tid < QPB) {
        int e = sub * QPB + tid;
        float R, C; bool m; int cs;
        edge_eval(qsdf, e, R, C, m, cs);
        if (m) {
            mycnt = 1.f;
            float best = BIGF;
            int ci = (int)R, cj = (int)C;
            // rings 0-1: 9 cells, 9 independent float4 loads
            #pragma unroll
            for (int di = -1; di <= 1; ++di) {
                #pragma unroll
                for (int dj = -1; dj <= 1; ++dj) {
                    int i = ci + di, j = cj + dj;
                    if ((unsigned)i < 64u && (unsigned)j < 64u)
                        scan_cell(cells, (i << 6) + j, R, C, best);
                }
            }
            // rings >= 2 (rare)
            for (int r = 2; r < 64 && best > (float)((r - 1) * (r - 1)); ++r) {
                int ilo = max(ci - r, 0), ihi = min(ci + r, 63);
                int jlo = max(cj - r, 0), jhi = min(cj + r, 63);
                for (int i = ilo; i <= ihi; ++i) {
                    if (i == ci - r || i == ci + r) {
                        for (int j = jlo; j <= jhi; ++j)
                            scan_cell(cells, (i << 6) + j, R, C, best);
                    } else {
                        if (cj - r >= 0) scan_cell(cells, (i << 6) + (cj - r), R, C, best);
                        if (cj + r <= 63) scan_cell(cells, (i << 6) + (cj + r), R, C, best);
                    }
                }
            }
            acc = sqrtf(best);
        }
    }

    // L1 slice: 16 float4 per block over flat [2048] float4 (2 images)
    float l1 = 0.f;
    if (tid < 16) {
        const float4* p4 = (const float4*)pred;
        const float4* g4 = (const float4*)gt;
        int idx = blk * 16 + tid;
        float4 a = p4[idx], bb = g4[idx];
        l1 = fabsf(a.x - bb.x) + fabsf(a.y - bb.y) + fabsf(a.z - bb.z) + fabsf(a.w - bb.w);
    }

    // block reduce (16 waves)
    for (int o = 32; o; o >>= 1) {
        acc   += __shfl_down(acc, o, 64);
        mycnt += __shfl_down(mycnt, o, 64);
        l1    += __shfl_down(l1, o, 64);
    }
    if (lane == 0) { redA[wid] = acc; redB[wid] = mycnt; redC[wid] = l1; }
    __syncthreads();
    if (tid == 0) {
        float sA = 0.f, sB = 0.f, sC = 0.f;
        #pragma unroll
        for (int w = 0; w < 16; ++w) { sA += redA[w]; sB += redB[w]; sC += redC[w]; }
        ws[blk] = sA;
        ws[128 + blk] = sB;
        ws[256 + blk] = sC;
    }
}

// 1 block, 256 threads: combine 128 sums/counts/L1 partials -> loss.
__global__ __launch_bounds__(256) void final_kernel(const float* __restrict__ ws,
                                                    float* __restrict__ out) {
    int tid = threadIdx.x, lane = tid & 63, wid = tid >> 6;
    __shared__ float sums[4], cnts[4], l1s[2];

    // wave w owns imgset w: 32 partials each
    float v = (lane < 32) ? ws[wid * 32 + lane] : 0.f;
    float c = (lane < 32) ? ws[128 + wid * 32 + lane] : 0.f;
    for (int o = 16; o; o >>= 1) { v += __shfl_down(v, o, 32); c += __shfl_down(c, o, 32); }
    if (lane == 0) { sums[wid] = v; cnts[wid] = c; }

    // L1: waves 0,1 own images 0,1: 64 partials each (img = blk>>6)
    float l = (wid < 2) ? ws[256 + wid * 64 + lane] : 0.f;
    for (int o = 32; o; o >>= 1) l += __shfl_down(l, o, 64);
    if (wid < 2 && lane == 0) l1s[wid] = l;
    __syncthreads();

    if (tid == 0) {
        float loss = 0.f;
        for (int b = 0; b < 2; ++b) {
            float mean1 = sums[2 * b + 0] / fmaxf(cnts[2 * b + 0], 1.f);  // pred->gt
            float mean2 = sums[2 * b + 1] / fmaxf(cnts[2 * b + 1], 1.f);  // gt->pred
            loss += l1s[b] * (1.f / (HH * WW)) + fabsf(-mean1 + mean2);
        }
        out[0] = loss * 0.5f;
    }
}

extern "C" void kernel_launch(void* const* d_in, const int* in_sizes, int n_in,
                              void* d_out, int out_size, void* d_ws, size_t ws_size,
                              hipStream_t stream) {
    const float* pred = (const float*)d_in[0];
    const float* gt   = (const float*)d_in[1];
    float* ws  = (float*)d_ws;
    float* out = (float*)d_out;

    hipLaunchKernelGGL(work_kernel,  dim3(128), dim3(1024), 0, stream, pred, gt, ws);
    hipLaunchKernelGGL(final_kernel, dim3(1),   dim3(256),  0, stream, ws, out);
}